// Round 1
// baseline (513.492 us; speedup 1.0000x reference)
//
#include <hip/hip_runtime.h>

// ROI Align (max) — R4: channel-loop restructure.
//
// R3 evidence: VALUBusy 72% / HBM 44% / 8M LDS-conflict cycles. The 32768
// (box, cg) blocks each redo identical coordinate/weight math that depends
// only on the box. R4: block = (box, xcd-chunk); loop over 8 channel-groups
// with ALL coordinate math, bilinear weights, LDS offsets and staging
// offsets hoisted out of the loop (loop body: 7 float4 loads + 7 LDS writes
// + 8 paired LDS reads + 20 VALU + 1 store).
//
// chunk = blockIdx&7 maps each channel-partition to one XCD (round-robin
// dispatch), so each plane is L2-resident on exactly one XCD -> HBM fetch
// ~feature-size instead of 2.5x.
//
// LDS row layout split as slot = s + 14*which (y0 rows 0..13, y1 rows
// 14..27) so the ph-varying compute reads stride 68 floats (4 banks/step)
// instead of 136 (2 banks alternating) -> fewer bank conflicts. Adjacent
// column pair (c0, c0+1) read as two dwords at base+0/+1 -> ds_read2_b32.
// c1==c0 clamp case: weight lx==0 and lds[c0+1] is always a written,
// finite value, so the extra lane is harmless.
//
// feature: (2, 256, 200, 304) fp32; boxes: (512,4); batch_idx: (512,) i32
// out: (512, 256, 7, 7) fp32. SPATIAL_SCALE=0.25, POOLED=7, SR=2, MODE=max.

#define SPATIAL_SCALE 0.25f
#define POOLED 7
#define SR 2

constexpr int Bc = 2;
constexpr int Cc = 256;
constexpr int Hc = 200;
constexpr int Wc = 304;
constexpr int Nc = 512;

constexpr int CG      = 4;               // channels per LDS tile
constexpr int NSAMP   = POOLED * SR;     // 14 sample coords per axis
constexpr int NROW    = NSAMP * 2;       // 28 row slots (y0 block, then y1 block)
constexpr int XW      = 64;              // staged columns (16 float4 lanes)
constexpr int XPAD    = 68;              // LDS row stride, floats
constexpr int CH_STR  = NROW * XPAD;     // 1904 floats per channel
constexpr int CELLS   = POOLED * POOLED; // 49
constexpr int OUTS    = CG * CELLS;      // 196 outputs per cg
constexpr int PER_BOX = Cc * CELLS;      // 12544
constexpr int PLANE   = Hc * Wc;         // 60800
constexpr int NCHUNK  = 8;               // one chunk per XCD
constexpr int JITER   = (Cc / CG) / NCHUNK;   // 8 cg-iterations per block
constexpr int JSTEP_PLANES = NCHUNK * CG;     // 32 planes advanced per iter

__global__ __launch_bounds__(256) void roi_align_max_kernel(
    const float* __restrict__ feature,
    const float* __restrict__ boxes,
    const int*   __restrict__ batch_idx,
    float*       __restrict__ out)
{
    __shared__ float lds[CG * CH_STR];   // 30,464 B -> 5 blocks/CU

    const int bid   = blockIdx.x;
    const int chunk = bid & (NCHUNK - 1);    // -> XCD (round-robin dispatch)
    const int n     = bid >> 3;              // box 0..511
    const int tid   = threadIdx.x;

    // ---- Box math (block-uniform; scalarizes) ----
    const float rsx = boxes[n * 4 + 0] * SPATIAL_SCALE;
    const float rsy = boxes[n * 4 + 1] * SPATIAL_SCALE;
    const float rex = boxes[n * 4 + 2] * SPATIAL_SCALE;
    const float rey = boxes[n * 4 + 3] * SPATIAL_SCALE;
    const float roi_w = fmaxf(rex - rsx, 1.0f);
    const float roi_h = fmaxf(rey - rsy, 1.0f);
    const float bin_w = roi_w / (float)POOLED;
    const float bin_h = roi_h / (float)POOLED;
    const int   b     = batch_idx[n];

    // xbase: aligned-down floor of the first x sample; span <= ~54 cols,
    // so [xbase, xbase+63] always covers every c0,c0+1 the compute reads.
    const float x_first = __fadd_rn(rsx, __fmul_rn(0.25f, bin_w));
    const float xc0     = fminf(fmaxf(x_first, 0.0f), (float)(Wc - 1));
    const int   xbase   = ((int)floorf(xc0)) & ~3;

    // ---- Staging metadata (loop-invariant) ----
    // wave c_st stages channel c_st; 7 iters x 4 row-quads x 16 float4 lanes.
    const int c_st   = tid >> 6;
    const int lane   = tid & 63;
    const int lane16 = lane & 15;
    const int rquad  = lane >> 4;

    int g_off[7];                        // element offset within a plane
    #pragma unroll
    for (int it = 0; it < 7; ++it) {
        const int slot  = it * 4 + rquad;      // 0..27 storage slot
        const int s     = slot % NSAMP;        // sample index 0..13
        const int which = slot / NSAMP;        // 0 -> y0 row, 1 -> y1 row
        const int p     = s >> 1;
        const int sub   = s & 1;
        const float py  = (float)p + ((float)sub + 0.5f) * 0.5f;
        const float fy  = __fadd_rn(rsy, __fmul_rn(py, bin_h));
        const float fyc = fminf(fmaxf(fy, 0.0f), (float)(Hc - 1));
        const int   y0  = (int)floorf(fyc);
        const int   row = which ? min(y0 + 1, Hc - 1) : y0;
        int col = xbase + lane16 * 4;
        col = min(col, Wc - 4);                // clamped cols never read
        g_off[it] = row * Wc + col;
    }
    const int lw = c_st * CH_STR + rquad * XPAD + lane16 * 4;  // +it*4*XPAD

    // plane base for j=0: channel = chunk*CG + c_st (cg = j*8 + chunk)
    const float* gp = feature
        + ((size_t)b * Cc + (size_t)chunk * CG + c_st) * (size_t)PLANE;

    // ---- Compute metadata (loop-invariant weights + LDS offsets) ----
    const bool has_out = (tid < OUTS);
    float w00[2][2], w01[2][2], w10[2][2], w11[2][2];
    int   adr[2][2][2];                  // [sy][row(y0/y1)][sx] float index
    float* outp = nullptr;

    if (has_out) {
        const int c_cl = tid / CELLS;
        const int cell = tid - c_cl * CELLS;
        const int ph   = cell / POOLED;
        const int pw   = cell - ph * POOLED;

        #pragma unroll
        for (int sy = 0; sy < SR; ++sy) {
            const int   sY  = ph * SR + sy;
            const float py  = (float)ph + ((float)sy + 0.5f) * 0.5f;
            const float fy  = __fadd_rn(rsy, __fmul_rn(py, bin_h));
            const bool  vy  = (fy > -1.0f) && (fy < (float)Hc);
            const float fyc = fminf(fmaxf(fy, 0.0f), (float)(Hc - 1));
            const int   y0i = (int)floorf(fyc);
            const float ly  = fyc - (float)y0i;
            const float hy  = 1.0f - ly;

            #pragma unroll
            for (int sx = 0; sx < SR; ++sx) {
                const float px  = (float)pw + ((float)sx + 0.5f) * 0.5f;
                const float fx  = __fadd_rn(rsx, __fmul_rn(px, bin_w));
                const bool  vx  = (fx > -1.0f) && (fx < (float)Wc);
                const float fxc = fminf(fmaxf(fx, 0.0f), (float)(Wc - 1));
                const int   x0i = (int)floorf(fxc);
                const float lx  = fxc - (float)x0i;
                const float hx  = 1.0f - lx;
                const int   c0  = x0i - xbase;
                const bool  v   = vy && vx;
                // validity folded into the weights: invalid tap -> bil = 0,
                // matching jnp.where(valid, val, 0) under the max.
                w00[sy][sx] = v ? hy * hx : 0.0f;
                w01[sy][sx] = v ? hy * lx : 0.0f;
                w10[sy][sx] = v ? ly * hx : 0.0f;
                w11[sy][sx] = v ? ly * lx : 0.0f;
                adr[sy][0][sx] = c_cl * CH_STR + sY * XPAD + c0;           // y0
                adr[sy][1][sx] = c_cl * CH_STR + (sY + NSAMP) * XPAD + c0; // y1
            }
        }
        outp = out + (size_t)n * PER_BOX
                   + ((size_t)chunk * CG + c_cl) * CELLS + cell;
    }

    // ---- Channel loop: 8 cg tiles, staging loads issued one iter ahead ----
    float4 st[7];
    #pragma unroll
    for (int it = 0; it < 7; ++it)
        st[it] = *(const float4*)(gp + g_off[it]);

    for (int j = 0; j < JITER; ++j) {
        #pragma unroll
        for (int it = 0; it < 7; ++it)
            *(float4*)&lds[lw + it * (4 * XPAD)] = st[it];

        if (j + 1 < JITER) {             // issue next tile's loads early (T14)
            gp += (size_t)JSTEP_PLANES * PLANE;
            #pragma unroll
            for (int it = 0; it < 7; ++it)
                st[it] = *(const float4*)(gp + g_off[it]);
        }

        __syncthreads();                 // staging writes visible

        if (has_out) {
            float m = -INFINITY;
            #pragma unroll
            for (int sy = 0; sy < SR; ++sy) {
                #pragma unroll
                for (int sx = 0; sx < SR; ++sx) {
                    const int a0 = adr[sy][0][sx];
                    const int a1 = adr[sy][1][sx];
                    const float v00 = lds[a0];
                    const float v01 = lds[a0 + 1];   // fuses to ds_read2_b32
                    const float v10 = lds[a1];
                    const float v11 = lds[a1 + 1];
                    const float bil = w00[sy][sx] * v00 + w01[sy][sx] * v01
                                    + w10[sy][sx] * v10 + w11[sy][sx] * v11;
                    m = fmaxf(m, bil);
                }
            }
            __builtin_nontemporal_store(m, outp);    // out is write-once
            outp += NCHUNK * CG * CELLS;             // next cg's channels
        }

        __syncthreads();                 // reads done before next writes
    }
}

extern "C" void kernel_launch(void* const* d_in, const int* in_sizes, int n_in,
                              void* d_out, int out_size, void* d_ws, size_t ws_size,
                              hipStream_t stream) {
    const float* feature   = (const float*)d_in[0];
    const float* boxes     = (const float*)d_in[1];
    const int*   batch_idx = (const int*)d_in[2];
    float*       out       = (float*)d_out;

    int grid = Nc * NCHUNK;              // 512 boxes x 8 XCD-chunks = 4096
    roi_align_max_kernel<<<grid, 256, 0, stream>>>(feature, boxes, batch_idx, out);
}

// Round 2
// 255.439 us; speedup vs baseline: 2.0102x; 2.0102x over previous
//
#include <hip/hip_runtime.h>

// ROI Align (max) — R5: R3 structure + per-box precompute table.
//
// R4 post-mortem: nontemporal 4B stores -> 790 MB HBM writes (31x); chunked
// channel mapping destroyed cg-cohort L2 locality (FETCH 303->650 MB).
// Reverted both. R4's VALU hoisting DID work (VALUBusy 72->3%), so R5 keeps
// R3's grid/dispatch/store structure and removes the redundant per-block
// coordinate math via a 512-block precompute kernel: per box we tabulate
// 49 cells x 4 taps x {4 weights, 2 LDS offsets}, 28 row offsets, xbase
// (4864 B/box, 2.5 MB in d_ws, L2-resident; each box's table is read by its
// 64 cg-blocks). Main kernel: staging addr = rowoff[slot] + col; compute =
// 4 x (2 ds_read2_b32 + mul + 3 fma + max) with preloaded weights.
//
// LDS layout split: y0 rows at slots 0..13, y1 rows at 14..27 -> compute
// row stride 68 floats (4 banks/sY step, 8/ph) instead of 136 (2-bank
// alternation) -> conflicts ~4-way -> ~2-way.
//
// feature: (2, 256, 200, 304) fp32; boxes: (512,4); batch_idx: (512,) i32
// out: (512, 256, 7, 7) fp32. SPATIAL_SCALE=0.25, POOLED=7, SR=2, MODE=max.

#define SPATIAL_SCALE 0.25f
#define POOLED 7
#define SR 2

constexpr int Bc = 2;
constexpr int Cc = 256;
constexpr int Hc = 200;
constexpr int Wc = 304;
constexpr int Nc = 512;

constexpr int CG      = 4;               // channels per block
constexpr int NSAMP   = POOLED * SR;     // 14 sample coords per axis
constexpr int NROW    = NSAMP * 2;       // 28 row slots (y0 block 0..13, y1 14..27)
constexpr int XPAD    = 68;              // LDS row stride, floats (16B-aligned)
constexpr int CH_STR  = NROW * XPAD;     // 1904 floats per channel
constexpr int CELLS   = POOLED * POOLED; // 49
constexpr int OUTS    = CG * CELLS;      // 196 outputs per block
constexpr int PER_BOX = Cc * CELLS;      // 12544
constexpr int PLANE   = Hc * Wc;         // 60800

// ---- per-box table layout (floats) ----
// [0 .. 783]     float4 w[cell][tap]   (cell*4 + tap float4s; tap = sy*2+sx)
// [784 .. 1175]  int    a[cell][tap][2] (a0 = sY*XPAD+c0, a1 = (14+sY)*XPAD+c0)
// [1176 .. 1203] int    rowoff[slot]   (row*Wc; slot = which*14 + s)
// [1204]         int    xbase
constexpr int TB_F  = 1216;              // floats per box (16B-aligned stride)
constexpr int A_OFF = 784;               // int index
constexpr int R_OFF = 1176;              // int index
constexpr int X_OFF = 1204;              // int index
constexpr size_t TABLE_BYTES = (size_t)Nc * TB_F * sizeof(float);

// ============================ precompute =============================
__global__ __launch_bounds__(64) void roi_precompute_kernel(
    const float* __restrict__ boxes,
    float*       __restrict__ table)
{
    const int n   = blockIdx.x;
    const int tid = threadIdx.x;

    const float rsx = boxes[n * 4 + 0] * SPATIAL_SCALE;
    const float rsy = boxes[n * 4 + 1] * SPATIAL_SCALE;
    const float rex = boxes[n * 4 + 2] * SPATIAL_SCALE;
    const float rey = boxes[n * 4 + 3] * SPATIAL_SCALE;
    const float roi_w = fmaxf(rex - rsx, 1.0f);
    const float roi_h = fmaxf(rey - rsy, 1.0f);
    const float bin_w = roi_w / (float)POOLED;
    const float bin_h = roi_h / (float)POOLED;
    const float x_first = __fadd_rn(rsx, __fmul_rn(0.25f, bin_w));
    const float xc0     = fminf(fmaxf(x_first, 0.0f), (float)(Wc - 1));
    const int   xbase   = ((int)floorf(xc0)) & ~3;

    float* tb = table + (size_t)n * TB_F;
    int*   ti = (int*)tb;

    if (tid < CELLS) {
        const int ph = tid / POOLED;
        const int pw = tid - ph * POOLED;
        #pragma unroll
        for (int sy = 0; sy < SR; ++sy) {
            const int   sY  = ph * SR + sy;
            const float py  = (float)ph + ((float)sy + 0.5f) * 0.5f;
            const float fy  = __fadd_rn(rsy, __fmul_rn(py, bin_h));
            const bool  vy  = (fy > -1.0f) && (fy < (float)Hc);
            const float fyc = fminf(fmaxf(fy, 0.0f), (float)(Hc - 1));
            const int   y0i = (int)floorf(fyc);
            const float ly  = fyc - (float)y0i;
            const float hy  = 1.0f - ly;
            #pragma unroll
            for (int sx = 0; sx < SR; ++sx) {
                const float px  = (float)pw + ((float)sx + 0.5f) * 0.5f;
                const float fx  = __fadd_rn(rsx, __fmul_rn(px, bin_w));
                const bool  vx  = (fx > -1.0f) && (fx < (float)Wc);
                const float fxc = fminf(fmaxf(fx, 0.0f), (float)(Wc - 1));
                const int   x0i = (int)floorf(fxc);
                const float lx  = fxc - (float)x0i;
                const float hx  = 1.0f - lx;
                const int   c0  = x0i - xbase;
                const bool  v   = vy && vx;      // fold validity into weights
                float4 w;
                w.x = v ? hy * hx : 0.0f;
                w.y = v ? hy * lx : 0.0f;
                w.z = v ? ly * hx : 0.0f;
                w.w = v ? ly * lx : 0.0f;
                const int tap = sy * SR + sx;
                ((float4*)tb)[tid * 4 + tap] = w;
                ti[A_OFF + tid * 8 + tap * 2 + 0] = sY * XPAD + c0;
                ti[A_OFF + tid * 8 + tap * 2 + 1] = (NSAMP + sY) * XPAD + c0;
            }
        }
    }
    if (tid < NROW) {
        const int which = tid / NSAMP;           // 0 -> y0 row, 1 -> y1 row
        const int s     = tid - which * NSAMP;
        const int p     = s >> 1;
        const int sub   = s & 1;
        const float py  = (float)p + ((float)sub + 0.5f) * 0.5f;
        const float fy  = __fadd_rn(rsy, __fmul_rn(py, bin_h));
        const float fyc = fminf(fmaxf(fy, 0.0f), (float)(Hc - 1));
        const int   y0  = (int)floorf(fyc);
        const int   row = which ? min(y0 + 1, Hc - 1) : y0;
        ti[R_OFF + tid] = row * Wc;
    }
    if (tid == 0) ti[X_OFF] = xbase;
}

// ============================== main =================================
__global__ __launch_bounds__(256) void roi_align_main_kernel(
    const float* __restrict__ feature,
    const int*   __restrict__ batch_idx,
    const float* __restrict__ table,
    float*       __restrict__ out)
{
    __shared__ float lds[CG * CH_STR];   // 30,464 B -> 5 blocks/CU

    const int bid = blockIdx.x;
    const int cg  = bid / Nc;            // cg outer: 512-block cohorts share L2
    const int n   = bid - cg * Nc;
    const int tid = threadIdx.x;

    const float* tb = table + (size_t)n * TB_F;
    const int*   ti = (const int*)tb;

    const int b     = batch_idx[n];
    const int xbase = ti[X_OFF];         // block-uniform -> scalar load

    // ---- staging metadata: row offsets from table ----
    const int c_st   = tid >> 6;         // wave = channel
    const int lane16 = tid & 15;
    const int rquad  = (tid >> 4) & 3;
    const int col    = min(xbase + lane16 * 4, Wc - 4); // clamped cols never read

    int roff[7];
    #pragma unroll
    for (int it = 0; it < 7; ++it)
        roff[it] = ti[R_OFF + it * 4 + rquad];          // slot = it*4+rquad

    // ---- compute metadata: tap records from table (issued early) ----
    const int cellc = min(tid, OUTS - 1);
    const int c_cl  = cellc / CELLS;
    const int cell  = cellc - c_cl * CELLS;
    const float4* wp = (const float4*)tb + (size_t)cell * 4;
    const float4 wv0 = wp[0], wv1 = wp[1], wv2 = wp[2], wv3 = wp[3];
    const int4* ap = (const int4*)(ti + A_OFF) + (size_t)cell * 2;
    const int4 av0 = ap[0], av1 = ap[1];

    // ---- staging: 4 channels x 28 rows x 64 cols ----
    const float* __restrict__ gbase =
        feature + ((size_t)b * Cc + (size_t)cg * CG + c_st) * (size_t)PLANE;
    float4 st[7];
    #pragma unroll
    for (int it = 0; it < 7; ++it)
        st[it] = *(const float4*)(gbase + roff[it] + col);

    const int lw = c_st * CH_STR + rquad * XPAD + lane16 * 4;
    #pragma unroll
    for (int it = 0; it < 7; ++it)
        *(float4*)&lds[lw + it * (4 * XPAD)] = st[it];

    __syncthreads();

    // ---- compute: 196 outputs, 4 taps each, all metadata preloaded ----
    if (tid < OUTS) {
        const int lbase = c_cl * CH_STR;
        float m = -INFINITY;
        {   const int a0 = av0.x + lbase, a1 = av0.y + lbase;
            const float bil = wv0.x * lds[a0] + wv0.y * lds[a0 + 1]
                            + wv0.z * lds[a1] + wv0.w * lds[a1 + 1];
            m = fmaxf(m, bil); }
        {   const int a0 = av0.z + lbase, a1 = av0.w + lbase;
            const float bil = wv1.x * lds[a0] + wv1.y * lds[a0 + 1]
                            + wv1.z * lds[a1] + wv1.w * lds[a1 + 1];
            m = fmaxf(m, bil); }
        {   const int a0 = av1.x + lbase, a1 = av1.y + lbase;
            const float bil = wv2.x * lds[a0] + wv2.y * lds[a0 + 1]
                            + wv2.z * lds[a1] + wv2.w * lds[a1 + 1];
            m = fmaxf(m, bil); }
        {   const int a0 = av1.z + lbase, a1 = av1.w + lbase;
            const float bil = wv3.x * lds[a0] + wv3.y * lds[a0 + 1]
                            + wv3.z * lds[a1] + wv3.w * lds[a1 + 1];
            m = fmaxf(m, bil); }
        out[(size_t)n * PER_BOX + cg * OUTS + tid] = m;   // plain store
    }
}

// ===================== fallback (verbatim R3 path) ====================
__global__ __launch_bounds__(256) void roi_align_max_fallback(
    const float* __restrict__ feature,
    const float* __restrict__ boxes,
    const int*   __restrict__ batch_idx,
    float*       __restrict__ out)
{
    __shared__ float lds[CG * CH_STR];

    int bid = blockIdx.x;
    int cg  = bid / Nc;
    int n   = bid - cg * Nc;
    int tid = threadIdx.x;

    float rsx = boxes[n * 4 + 0] * SPATIAL_SCALE;
    float rsy = boxes[n * 4 + 1] * SPATIAL_SCALE;
    float rex = boxes[n * 4 + 2] * SPATIAL_SCALE;
    float rey = boxes[n * 4 + 3] * SPATIAL_SCALE;
    float roi_w = fmaxf(rex - rsx, 1.0f);
    float roi_h = fmaxf(rey - rsy, 1.0f);
    float bin_w = roi_w / (float)POOLED;
    float bin_h = roi_h / (float)POOLED;
    int b = batch_idx[n];

    float x_first = __fadd_rn(rsx, __fmul_rn(0.25f, bin_w));
    float xc0 = fminf(fmaxf(x_first, 0.0f), (float)(Wc - 1));
    int xbase = ((int)floorf(xc0)) & ~3;

    const float* __restrict__ gbase =
        feature + ((size_t)b * Cc + (size_t)cg * CG) * (size_t)PLANE;

    int lane16 = tid & 15;
    int rbase  = tid >> 4;
    #pragma unroll
    for (int it = 0; it < 7; ++it) {
        int r       = it * 16 + rbase;
        int c_local = r / NROW;
        int slot    = r - c_local * NROW;
        int s       = slot % NSAMP;
        int which   = slot / NSAMP;
        int p       = s >> 1;
        int sub     = s & 1;
        float py = (float)p + ((float)sub + 0.5f) * 0.5f;
        float fy = __fadd_rn(rsy, __fmul_rn(py, bin_h));
        float fyc = fminf(fmaxf(fy, 0.0f), (float)(Hc - 1));
        int y0 = (int)floorf(fyc);
        int row = which ? min(y0 + 1, Hc - 1) : y0;
        int colf = min(xbase + lane16 * 4, Wc - 4);
        const float4 v = *(const float4*)(gbase + (size_t)c_local * PLANE
                                          + row * Wc + colf);
        *(float4*)&lds[c_local * CH_STR + slot * XPAD + lane16 * 4] = v;
    }
    __syncthreads();

    if (tid < OUTS) {
        int c_local = tid / CELLS;
        int cell    = tid - c_local * CELLS;
        int ph      = cell / POOLED;
        int pw      = cell - ph * POOLED;
        const float* __restrict__ L = &lds[c_local * CH_STR];

        float m = -INFINITY;
        #pragma unroll
        for (int sy = 0; sy < SR; ++sy) {
            int sY = ph * SR + sy;
            float py = (float)ph + ((float)sy + 0.5f) * 0.5f;
            float fy = __fadd_rn(rsy, __fmul_rn(py, bin_h));
            bool vy = (fy > -1.0f) && (fy < (float)Hc);
            float fyc = fminf(fmaxf(fy, 0.0f), (float)(Hc - 1));
            int y0 = (int)floorf(fyc);
            float ly = fyc - (float)y0;
            float hy = 1.0f - ly;
            const float* __restrict__ r0 = L + sY * XPAD;
            const float* __restrict__ r1 = L + (NSAMP + sY) * XPAD;

            #pragma unroll
            for (int sx = 0; sx < SR; ++sx) {
                float px = (float)pw + ((float)sx + 0.5f) * 0.5f;
                float fx = __fadd_rn(rsx, __fmul_rn(px, bin_w));
                bool vx = (fx > -1.0f) && (fx < (float)Wc);
                float fxc = fminf(fmaxf(fx, 0.0f), (float)(Wc - 1));
                int x0 = (int)floorf(fxc);
                float lx = fxc - (float)x0;
                float hx = 1.0f - lx;
                int c0 = x0 - xbase;

                float v00 = r0[c0], v01 = r0[c0 + 1];
                float v10 = r1[c0], v11 = r1[c0 + 1];
                float bil = hy * hx * v00 + hy * lx * v01 +
                            ly * hx * v10 + ly * lx * v11;
                float v = (vy && vx) ? bil : 0.0f;
                m = fmaxf(m, v);
            }
        }
        out[(size_t)n * PER_BOX + cg * OUTS + tid] = m;
    }
}

extern "C" void kernel_launch(void* const* d_in, const int* in_sizes, int n_in,
                              void* d_out, int out_size, void* d_ws, size_t ws_size,
                              hipStream_t stream) {
    const float* feature   = (const float*)d_in[0];
    const float* boxes     = (const float*)d_in[1];
    const int*   batch_idx = (const int*)d_in[2];
    float*       out       = (float*)d_out;

    const int grid = (Cc / CG) * Nc;     // 64 * 512 = 32768, cg-outer
    if (d_ws != nullptr && ws_size >= TABLE_BYTES) {
        float* table = (float*)d_ws;
        roi_precompute_kernel<<<Nc, 64, 0, stream>>>(boxes, table);
        roi_align_main_kernel<<<grid, 256, 0, stream>>>(feature, batch_idx,
                                                        table, out);
    } else {
        roi_align_max_fallback<<<grid, 256, 0, stream>>>(feature, boxes,
                                                         batch_idx, out);
    }
}

// Round 3
// 236.506 us; speedup vs baseline: 2.1712x; 1.0801x over previous
//
#include <hip/hip_runtime.h>

// ROI Align (max) — R6: dynamic-span staging + cooperative row offsets.
//
// R5 post-mortem: VALU hoist worked (72->14.5%) but kernel became
// latency-bound (HBM 35%, dur 95.6->120.7): per-thread table gather of row
// offsets serialized a second memory round trip before feature loads.
// R6 changes:
//  1. Stage only ceil(span/4) float4 lanes instead of fixed 16 (avg box
//     needs ~30 of 64 cols) -> FETCH ~304 -> ~190 MB. Exec-mask predication.
//  2. Row offsets computed cooperatively in-kernel (28 threads -> 112B LDS
//     array): feature loads depend only on the scalar boxes[] load.
//     Table keeps only compute-phase weights/addresses (off critical path).
//  3. XPAD 68->60 (span <= 56): LDS 30.5->27.0 KB -> 6 blocks/CU (24 waves).
//
// feature: (2, 256, 200, 304) fp32; boxes: (512,4); batch_idx: (512,) i32
// out: (512, 256, 7, 7) fp32. SPATIAL_SCALE=0.25, POOLED=7, SR=2, MODE=max.

#define SPATIAL_SCALE 0.25f
#define POOLED 7
#define SR 2

constexpr int Bc = 2;
constexpr int Cc = 256;
constexpr int Hc = 200;
constexpr int Wc = 304;
constexpr int Nc = 512;

constexpr int CG      = 4;               // channels per block
constexpr int NSAMP   = POOLED * SR;     // 14 sample coords per axis
constexpr int NROW    = NSAMP * 2;       // 28 row slots (y0 0..13, y1 14..27)
constexpr int XPAD    = 60;              // LDS row stride (span<=54, writes<=56, +guard)
constexpr int CH_STR  = NROW * XPAD;     // 1680 floats per channel
constexpr int CELLS   = POOLED * POOLED; // 49
constexpr int OUTS    = CG * CELLS;      // 196 outputs per block
constexpr int PER_BOX = Cc * CELLS;      // 12544
constexpr int PLANE   = Hc * Wc;         // 60800

// ---- per-box table layout (floats) ----
// [0 .. 783]     float4 w[cell][tap]    (tap = sy*2+sx)
// [784 .. 1175]  int    a[cell][tap][2] (a0 = sY*XPAD+c0, a1 = (14+sY)*XPAD+c0)
// [1176 .. 1203] (unused in main; kept for layout stability)
// [1204]         int    xbase (unused in main)
constexpr int TB_F  = 1216;
constexpr int A_OFF = 784;
constexpr int R_OFF = 1176;
constexpr int X_OFF = 1204;
constexpr size_t TABLE_BYTES = (size_t)Nc * TB_F * sizeof(float);

// ============================ precompute =============================
__global__ __launch_bounds__(64) void roi_precompute_kernel(
    const float* __restrict__ boxes,
    float*       __restrict__ table)
{
    const int n   = blockIdx.x;
    const int tid = threadIdx.x;

    const float rsx = boxes[n * 4 + 0] * SPATIAL_SCALE;
    const float rsy = boxes[n * 4 + 1] * SPATIAL_SCALE;
    const float rex = boxes[n * 4 + 2] * SPATIAL_SCALE;
    const float rey = boxes[n * 4 + 3] * SPATIAL_SCALE;
    const float roi_w = fmaxf(rex - rsx, 1.0f);
    const float roi_h = fmaxf(rey - rsy, 1.0f);
    const float bin_w = roi_w / (float)POOLED;
    const float bin_h = roi_h / (float)POOLED;
    const float x_first = __fadd_rn(rsx, __fmul_rn(0.25f, bin_w));
    const float xc0     = fminf(fmaxf(x_first, 0.0f), (float)(Wc - 1));
    const int   xbase   = ((int)floorf(xc0)) & ~3;

    float* tb = table + (size_t)n * TB_F;
    int*   ti = (int*)tb;

    if (tid < CELLS) {
        const int ph = tid / POOLED;
        const int pw = tid - ph * POOLED;
        #pragma unroll
        for (int sy = 0; sy < SR; ++sy) {
            const int   sY  = ph * SR + sy;
            const float py  = (float)ph + ((float)sy + 0.5f) * 0.5f;
            const float fy  = __fadd_rn(rsy, __fmul_rn(py, bin_h));
            const bool  vy  = (fy > -1.0f) && (fy < (float)Hc);
            const float fyc = fminf(fmaxf(fy, 0.0f), (float)(Hc - 1));
            const int   y0i = (int)floorf(fyc);
            const float ly  = fyc - (float)y0i;
            const float hy  = 1.0f - ly;
            #pragma unroll
            for (int sx = 0; sx < SR; ++sx) {
                const float px  = (float)pw + ((float)sx + 0.5f) * 0.5f;
                const float fx  = __fadd_rn(rsx, __fmul_rn(px, bin_w));
                const bool  vx  = (fx > -1.0f) && (fx < (float)Wc);
                const float fxc = fminf(fmaxf(fx, 0.0f), (float)(Wc - 1));
                const int   x0i = (int)floorf(fxc);
                const float lx  = fxc - (float)x0i;
                const float hx  = 1.0f - lx;
                const int   c0  = x0i - xbase;
                const bool  v   = vy && vx;      // fold validity into weights
                float4 w;
                w.x = v ? hy * hx : 0.0f;
                w.y = v ? hy * lx : 0.0f;
                w.z = v ? ly * hx : 0.0f;
                w.w = v ? ly * lx : 0.0f;
                const int tap = sy * SR + sx;
                ((float4*)tb)[tid * 4 + tap] = w;
                ti[A_OFF + tid * 8 + tap * 2 + 0] = sY * XPAD + c0;
                ti[A_OFF + tid * 8 + tap * 2 + 1] = (NSAMP + sY) * XPAD + c0;
            }
        }
    }
    if (tid < NROW) {                    // kept for layout stability
        const int which = tid / NSAMP;
        const int s     = tid - which * NSAMP;
        const float py  = fmaf((float)s, 0.5f, 0.25f);
        const float fy  = __fadd_rn(rsy, __fmul_rn(py, bin_h));
        const float fyc = fminf(fmaxf(fy, 0.0f), (float)(Hc - 1));
        const int   y0  = (int)floorf(fyc);
        const int   row = which ? min(y0 + 1, Hc - 1) : y0;
        ti[R_OFF + tid] = row * Wc;
    }
    if (tid == 0) ti[X_OFF] = xbase;
}

// ============================== main =================================
__global__ __launch_bounds__(256) void roi_align_main_kernel(
    const float* __restrict__ feature,
    const float* __restrict__ boxes,
    const int*   __restrict__ batch_idx,
    const float* __restrict__ table,
    float*       __restrict__ out)
{
    __shared__ float lds[CG * CH_STR];   // 26,880 B
    __shared__ int   rowoff_sh[NROW];    // +112 B -> 6 blocks/CU

    const int bid = blockIdx.x;
    const int cg  = bid >> 9;            // cg outer: 512-block cohorts share L2
    const int n   = bid & (Nc - 1);
    const int tid = threadIdx.x;

    // ---- compute-phase table loads: issued at kernel start, consumed
    //      after the barrier -> latency fully hidden under staging ----
    const float* tb = table + (size_t)n * TB_F;
    const int*   ti = (const int*)tb;
    const int cellc = min(tid, OUTS - 1);
    const int c_cl  = cellc / CELLS;
    const int cell  = cellc - c_cl * CELLS;
    const float4* wp = (const float4*)tb + (size_t)cell * 4;
    const float4 wv0 = wp[0], wv1 = wp[1], wv2 = wp[2], wv3 = wp[3];
    const int4* ap = (const int4*)(ti + A_OFF) + (size_t)cell * 2;
    const int4 av0 = ap[0], av1 = ap[1];

    // ---- box math (block-uniform -> scalar) ----
    const float rsx = boxes[n * 4 + 0] * SPATIAL_SCALE;
    const float rsy = boxes[n * 4 + 1] * SPATIAL_SCALE;
    const float rex = boxes[n * 4 + 2] * SPATIAL_SCALE;
    const float rey = boxes[n * 4 + 3] * SPATIAL_SCALE;
    const float roi_w = fmaxf(rex - rsx, 1.0f);
    const float roi_h = fmaxf(rey - rsy, 1.0f);
    const float bin_w = roi_w / (float)POOLED;
    const float bin_h = roi_h / (float)POOLED;
    const int   b     = batch_idx[n];

    const float x_first = __fadd_rn(rsx, __fmul_rn(0.25f, bin_w));
    const float xc0     = fminf(fmaxf(x_first, 0.0f), (float)(Wc - 1));
    const int   xbase   = ((int)floorf(xc0)) & ~3;

    // dynamic span: last x sample is index 13 (px = 6.75), monotone max.
    const float x_last = __fadd_rn(rsx, __fmul_rn(6.75f, bin_w));
    const float xlc    = fminf(fmaxf(x_last, 0.0f), (float)(Wc - 1));
    const int   x0l    = (int)floorf(xlc);
    const int   xlastc = min(x0l + 1, Wc - 1);
    const int   span   = xlastc - xbase + 1;      // <= 54
    const int   nl4    = (span + 4) >> 2;         // +1 col guard; <= 14

    // ---- cooperative row offsets (28 threads; py = 0.5*s + 0.25 exact) ----
    if (tid < NROW) {
        const int  which = tid >= NSAMP;
        const int  s     = which ? tid - NSAMP : tid;
        const float py   = fmaf((float)s, 0.5f, 0.25f);
        const float fy   = __fadd_rn(rsy, __fmul_rn(py, bin_h));
        const float fyc  = fminf(fmaxf(fy, 0.0f), (float)(Hc - 1));
        const int   y0   = (int)floorf(fyc);
        const int   row  = which ? min(y0 + 1, Hc - 1) : y0;
        rowoff_sh[tid] = row * Wc;
    }
    __syncthreads();

    // ---- staging: 4 ch x 28 rows x (4*nl4) cols, predicated lanes ----
    const int c_st   = tid >> 6;
    const int lane16 = tid & 15;
    const int rquad  = (tid >> 4) & 3;
    const float* __restrict__ gplane =
        feature + ((size_t)b * Cc + (size_t)cg * CG + c_st) * (size_t)PLANE;
    const int col = min(xbase + lane16 * 4, Wc - 4);

    if (lane16 < nl4) {
        int ro[7];
        #pragma unroll
        for (int it = 0; it < 7; ++it)
            ro[it] = rowoff_sh[it * 4 + rquad];       // broadcast reads
        float4 st[7];
        #pragma unroll
        for (int it = 0; it < 7; ++it)
            st[it] = *(const float4*)(gplane + ro[it] + col);
        const int lw = c_st * CH_STR + rquad * XPAD + lane16 * 4;
        #pragma unroll
        for (int it = 0; it < 7; ++it)
            *(float4*)&lds[lw + it * (4 * XPAD)] = st[it];
    }
    __syncthreads();

    // ---- compute: 196 outputs, 4 taps each, all metadata preloaded ----
    if (tid < OUTS) {
        const int lbase = c_cl * CH_STR;
        float m = -INFINITY;
        {   const int a0 = av0.x + lbase, a1 = av0.y + lbase;
            const float bil = wv0.x * lds[a0] + wv0.y * lds[a0 + 1]
                            + wv0.z * lds[a1] + wv0.w * lds[a1 + 1];
            m = fmaxf(m, bil); }
        {   const int a0 = av0.z + lbase, a1 = av0.w + lbase;
            const float bil = wv1.x * lds[a0] + wv1.y * lds[a0 + 1]
                            + wv1.z * lds[a1] + wv1.w * lds[a1 + 1];
            m = fmaxf(m, bil); }
        {   const int a0 = av1.x + lbase, a1 = av1.y + lbase;
            const float bil = wv2.x * lds[a0] + wv2.y * lds[a0 + 1]
                            + wv2.z * lds[a1] + wv2.w * lds[a1 + 1];
            m = fmaxf(m, bil); }
        {   const int a0 = av1.z + lbase, a1 = av1.w + lbase;
            const float bil = wv3.x * lds[a0] + wv3.y * lds[a0 + 1]
                            + wv3.z * lds[a1] + wv3.w * lds[a1 + 1];
            m = fmaxf(m, bil); }
        out[(size_t)n * PER_BOX + cg * OUTS + tid] = m;   // plain store
    }
}

// ===================== fallback (verbatim R3 path) ====================
constexpr int XPAD_FB   = 68;
constexpr int CH_STR_FB = NROW * XPAD_FB;

__global__ __launch_bounds__(256) void roi_align_max_fallback(
    const float* __restrict__ feature,
    const float* __restrict__ boxes,
    const int*   __restrict__ batch_idx,
    float*       __restrict__ out)
{
    __shared__ float lds[CG * CH_STR_FB];

    int bid = blockIdx.x;
    int cg  = bid / Nc;
    int n   = bid - cg * Nc;
    int tid = threadIdx.x;

    float rsx = boxes[n * 4 + 0] * SPATIAL_SCALE;
    float rsy = boxes[n * 4 + 1] * SPATIAL_SCALE;
    float rex = boxes[n * 4 + 2] * SPATIAL_SCALE;
    float rey = boxes[n * 4 + 3] * SPATIAL_SCALE;
    float roi_w = fmaxf(rex - rsx, 1.0f);
    float roi_h = fmaxf(rey - rsy, 1.0f);
    float bin_w = roi_w / (float)POOLED;
    float bin_h = roi_h / (float)POOLED;
    int b = batch_idx[n];

    float x_first = __fadd_rn(rsx, __fmul_rn(0.25f, bin_w));
    float xc0 = fminf(fmaxf(x_first, 0.0f), (float)(Wc - 1));
    int xbase = ((int)floorf(xc0)) & ~3;

    const float* __restrict__ gbase =
        feature + ((size_t)b * Cc + (size_t)cg * CG) * (size_t)PLANE;

    int lane16 = tid & 15;
    int rbase  = tid >> 4;
    #pragma unroll
    for (int it = 0; it < 7; ++it) {
        int r       = it * 16 + rbase;
        int c_local = r / NROW;
        int slot    = r - c_local * NROW;
        int s       = slot % NSAMP;
        int which   = slot / NSAMP;
        float py = fmaf((float)s, 0.5f, 0.25f);
        float fy = __fadd_rn(rsy, __fmul_rn(py, bin_h));
        float fyc = fminf(fmaxf(fy, 0.0f), (float)(Hc - 1));
        int y0 = (int)floorf(fyc);
        int row = which ? min(y0 + 1, Hc - 1) : y0;
        int colf = min(xbase + lane16 * 4, Wc - 4);
        const float4 v = *(const float4*)(gbase + (size_t)c_local * PLANE
                                          + row * Wc + colf);
        *(float4*)&lds[c_local * CH_STR_FB + slot * XPAD_FB + lane16 * 4] = v;
    }
    __syncthreads();

    if (tid < OUTS) {
        int c_local = tid / CELLS;
        int cell    = tid - c_local * CELLS;
        int ph      = cell / POOLED;
        int pw      = cell - ph * POOLED;
        const float* __restrict__ L = &lds[c_local * CH_STR_FB];

        float m = -INFINITY;
        #pragma unroll
        for (int sy = 0; sy < SR; ++sy) {
            int sY = ph * SR + sy;
            float py = (float)ph + ((float)sy + 0.5f) * 0.5f;
            float fy = __fadd_rn(rsy, __fmul_rn(py, bin_h));
            bool vy = (fy > -1.0f) && (fy < (float)Hc);
            float fyc = fminf(fmaxf(fy, 0.0f), (float)(Hc - 1));
            int y0 = (int)floorf(fyc);
            float ly = fyc - (float)y0;
            float hy = 1.0f - ly;
            const float* __restrict__ r0 = L + sY * XPAD_FB;
            const float* __restrict__ r1 = L + (NSAMP + sY) * XPAD_FB;

            #pragma unroll
            for (int sx = 0; sx < SR; ++sx) {
                float px = (float)pw + ((float)sx + 0.5f) * 0.5f;
                float fx = __fadd_rn(rsx, __fmul_rn(px, bin_w));
                bool vx = (fx > -1.0f) && (fx < (float)Wc);
                float fxc = fminf(fmaxf(fx, 0.0f), (float)(Wc - 1));
                int x0 = (int)floorf(fxc);
                float lx = fxc - (float)x0;
                float hx = 1.0f - lx;
                int c0 = x0 - xbase;

                float v00 = r0[c0], v01 = r0[c0 + 1];
                float v10 = r1[c0], v11 = r1[c0 + 1];
                float bil = hy * hx * v00 + hy * lx * v01 +
                            ly * hx * v10 + ly * lx * v11;
                float v = (vy && vx) ? bil : 0.0f;
                m = fmaxf(m, v);
            }
        }
        out[(size_t)n * PER_BOX + cg * OUTS + tid] = m;
    }
}

extern "C" void kernel_launch(void* const* d_in, const int* in_sizes, int n_in,
                              void* d_out, int out_size, void* d_ws, size_t ws_size,
                              hipStream_t stream) {
    const float* feature   = (const float*)d_in[0];
    const float* boxes     = (const float*)d_in[1];
    const int*   batch_idx = (const int*)d_in[2];
    float*       out       = (float*)d_out;

    const int grid = (Cc / CG) * Nc;     // 64 * 512 = 32768, cg-outer
    if (d_ws != nullptr && ws_size >= TABLE_BYTES) {
        float* table = (float*)d_ws;
        roi_precompute_kernel<<<Nc, 64, 0, stream>>>(boxes, table);
        roi_align_main_kernel<<<grid, 256, 0, stream>>>(feature, boxes,
                                                        batch_idx, table, out);
    } else {
        roi_align_max_fallback<<<grid, 256, 0, stream>>>(feature, boxes,
                                                         batch_idx, out);
    }
}